// Round 13
// baseline (563.883 us; speedup 1.0000x reference)
//
#include <hip/hip_runtime.h>
#include <hip/hip_bf16.h>
#include <math.h>

#define NTHREADS 256
#define BR 64          // fused-fallback tile
#define MTHREADS 512   // mlp threads
#define MBR 128        // mlp point tile

typedef __attribute__((ext_vector_type(8))) short   s16x8;
typedef __attribute__((ext_vector_type(8))) __bf16  bf16x8;
typedef __attribute__((ext_vector_type(4))) float   f32x4;
typedef __attribute__((ext_vector_type(2))) float   f32x2;

// ---- Compile-time hash-grid constants (verified exact: absmax 0.0 rounds 1,3,4,6-11) ----
__device__ __constant__ float c_scale[16] = {
    15.0f,        21.110607f,  29.554930f,  41.224254f,
    57.350239f,   79.634946f,  110.430473f, 152.987205f,
    211.796890f,  293.066769f, 405.374657f, 560.574388f,
    775.046906f,  1071.429232f, 1481.003616f, 2047.0f
};
__device__ __constant__ unsigned c_off[16] = {
    0u,        4920u,     18744u,    51512u,
    136696u,   352696u,   876984u,   1401272u,
    1925560u,  2449848u,  2974136u,  3498424u,
    4022712u,  4547000u,  5071288u,  5595576u
};
__device__ __constant__ unsigned c_res1[16] = {
    17u, 24u, 32u, 44u, 60u, 0u,0u,0u,0u,0u,0u,0u,0u,0u,0u,0u
};

#define TBL_SCALE     8192.0f
#define TBL_SCALE_INV (1.0f/8192.0f)

__device__ inline unsigned short f2bf(float f) {
    unsigned u = __builtin_bit_cast(unsigned, f);
    u += 0x7FFFu + ((u >> 16) & 1u);          // round-to-nearest-even
    return (unsigned short)(u >> 16);
}
__device__ inline float bf2f(unsigned short h) {
    unsigned u = ((unsigned)h) << 16;
    return __builtin_bit_cast(float, u);
}
__device__ inline unsigned cvtpk(float lo, float hi) {
    unsigned r;
    asm("v_cvt_pk_bf16_f32 %0, %1, %2" : "=v"(r) : "v"(lo), "v"(hi));
    return r;
}
__device__ inline f32x4 mfma_bf16(s16x8 a, s16x8 b, f32x4 c) {
    return __builtin_amdgcn_mfma_f32_16x16x32_bf16(
        __builtin_bit_cast(bf16x8, a), __builtin_bit_cast(bf16x8, b), c, 0, 0, 0);
}

// ws layout (bytes): wt bf16[143360] @0 ; fp8 table ushort[TOTAL] @286720 ;
// feat2 uint2[8][N] @12526448.
__global__ void convert_w(const float* __restrict__ w1, const float* __restrict__ w2,
                          const float* __restrict__ w3, const float* __restrict__ w4,
                          unsigned short* __restrict__ ws) {
    int t = blockIdx.x * blockDim.x + threadIdx.x;
    if (t < 8192) {
        int col = t >> 5, k = t & 31;
        ws[t] = f2bf(w1[k * 256 + col]);
    } else if (t < 73728) {
        int u = t - 8192; int col = u >> 8, k = u & 255;
        ws[t] = f2bf(w2[k * 256 + col]);
    } else if (t < 139264) {
        int u = t - 73728; int col = u >> 8, k = u & 255;
        ws[t] = f2bf(w3[k * 256 + col]);
    } else if (t < 143360) {
        int u = t - 139264; int ch = u >> 8, k = u & 255;
        ws[t] = (ch < 3) ? f2bf(w4[k * 3 + ch]) : (unsigned short)0;
    }
}

__global__ void convert_table_fp8(const float* __restrict__ t, unsigned short* __restrict__ o, int n) {
    int i = blockIdx.x * blockDim.x + threadIdx.x;
    if (i < n) {
        const float2 v = ((const float2*)t)[i];
        const int pk = __builtin_amdgcn_cvt_pk_fp8_f32(v.x * TBL_SCALE, v.y * TBL_SCALE, 0, false);
        o[i] = (unsigned short)(pk & 0xFFFF);
    }
}

// ---- encode: r12 x-pair dword merge. Corner pairs (bx=0,1) share (by,bz);
// dense: i1=i0+1; hash (PRIME0=1): i1=i0^1 when ux even. A dword at (i0&~1)
// ALWAYS holds i0 and holds i1 when i1==i0^1 (~50%) -> loads/pair 2 -> 1.5,
// TA transactions -25% (encode was TA-bound at 2.1x the 109us floor). ----
__global__ __launch_bounds__(256)
void encode_kernel(const float* __restrict__ x, const unsigned short* __restrict__ tbf8,
                   uint2* __restrict__ feat2, int N)
{
    const int p  = blockIdx.x * 256 + threadIdx.x;
    const int lp = blockIdx.y;                 // 0..7, wave-uniform
    if (p >= N) return;

    const float inv = (1.0f / 1.5f);
    const float xc = x[3 * p + 0] * inv;
    const float yc = x[3 * p + 1] * inv;
    const float zc = x[3 * p + 2] * inv;

    unsigned i0a[2][4], i1a[2][4];
    float rxa[2], rya[2], rza[2];
    #pragma unroll
    for (int s = 0; s < 2; ++s) {
        const int l = lp * 2 + s;              // uniform
        const float sc = c_scale[l];
        const float px = xc * sc + 0.5f;
        const float py = yc * sc + 0.5f;
        const float pz = zc * sc + 0.5f;
        const float fx = floorf(px), fy = floorf(py), fz = floorf(pz);
        rxa[s] = px - fx; rya[s] = py - fy; rza[s] = pz - fz;
        const unsigned ux = (unsigned)fx, uy = (unsigned)fy, uz = (unsigned)fz;
        const unsigned off = c_off[l];
        const unsigned r1  = c_res1[l];
        const bool dense = (l < 5);            // uniform
        #pragma unroll
        for (int j = 0; j < 4; ++j) {          // pair j: corners (2j, 2j+1); by=j&1, bz=j>>1
            const unsigned cy = uy + (j & 1), cz = uz + (j >> 1);
            unsigned i0, i1;
            if (dense) {
                i0 = ux + cy * r1 + cz * r1 * r1;
                i1 = i0 + 1;
            } else {
                const unsigned m = (cy * 2654435761u) ^ (cz * 805459861u);
                i0 = (ux ^ m) & 524287u;
                i1 = ((ux + 1u) ^ m) & 524287u;
            }
            i0a[s][j] = i0 + off;
            i1a[s][j] = i1 + off;
        }
    }

    // 8 dword loads (aligned: entries 2B, (i0&~1) even; offsets all even)
    unsigned da[2][4];
    #pragma unroll
    for (int s = 0; s < 2; ++s)
        #pragma unroll
        for (int j = 0; j < 4; ++j)
            da[s][j] = *reinterpret_cast<const unsigned*>(tbf8 + (i0a[s][j] & ~1u));

    // predicated fallback word loads for non-adjacent i1 (~50% of lanes)
    unsigned short fb[2][4];
    #pragma unroll
    for (int s = 0; s < 2; ++s)
        #pragma unroll
        for (int j = 0; j < 4; ++j) {
            const bool merged = ((i0a[s][j] ^ 1u) == i1a[s][j]);
            fb[s][j] = merged ? (unsigned short)0 : tbf8[i1a[s][j]];
        }

    // consume
    unsigned outv[2];
    #pragma unroll
    for (int s = 0; s < 2; ++s) {
        float ax = 0.0f, ay = 0.0f;
        #pragma unroll
        for (int j = 0; j < 4; ++j) {
            const unsigned i0 = i0a[s][j], i1 = i1a[s][j], d = da[s][j];
            const unsigned short v0 = (i0 & 1) ? (unsigned short)(d >> 16)
                                               : (unsigned short)(d & 0xFFFFu);
            const bool merged = ((i0 ^ 1u) == i1);
            const unsigned short vm = (i1 & 1) ? (unsigned short)(d >> 16)
                                               : (unsigned short)(d & 0xFFFFu);
            const unsigned short v1 = merged ? vm : fb[s][j];
            const float wy = (j & 1) ? rya[s] : (1.0f - rya[s]);
            const float wz = (j >> 1) ? rza[s] : (1.0f - rza[s]);
            const float wyz = wy * wz;
            const float w0 = (1.0f - rxa[s]) * wyz;
            const float w1 = rxa[s] * wyz;
            const f32x2 t0 = __builtin_amdgcn_cvt_pk_f32_fp8((int)v0, false);
            const f32x2 t1 = __builtin_amdgcn_cvt_pk_f32_fp8((int)v1, false);
            ax = fmaf(w0, t0[0], ax); ay = fmaf(w0, t0[1], ay);
            ax = fmaf(w1, t1[0], ax); ay = fmaf(w1, t1[1], ay);
        }
        outv[s] = cvtpk(ax * TBL_SCALE_INV, ay * TBL_SCALE_INV);
    }
    feat2[(size_t)lp * N + p] = make_uint2(outv[0], outv[1]);
}

// ---- MLP r12: MBR=128 points, 512 threads (8 waves = 4 feature-slices x 2 point-halves).
// LDS 64KB -> 2 blocks/CU -> same 16 waves/CU, but weight fragments serve 2x points
// (waves 0-3/4-7 share slices via L1) and barriers per point halve.
// __launch_bounds__(512,4): 128-reg budget = 64 arch + 64 acc (r8 allocation). ----
__global__ __launch_bounds__(MTHREADS, 4)
void mlp_kernel(const uint2* __restrict__ feat2,
                const unsigned short* __restrict__ wt,
                const float* __restrict__ b1, const float* __restrict__ b2,
                const float* __restrict__ b3, const float* __restrict__ b4,
                float* __restrict__ out, int N)
{
    __shared__ unsigned short sA[MBR * 256];   // 64 KB, rows of 512B, XOR-swizzled
    char* sAb = (char*)sA;

    const int tid = threadIdx.x;
    const int p0  = blockIdx.x * MBR;
    if (p0 >= N) return;

    // ---- A-tile load: 1024 uint2 (8 planes x 128 points) ----
    #pragma unroll
    for (int it = 0; it < 2; ++it) {
        const int t  = it * MTHREADS + tid;
        const int lp = t >> 7;                 // plane 0..7
        const int pp = t & 127;
        const uint2 v = feat2[(size_t)lp * N + p0 + pp];
        *reinterpret_cast<uint2*>(
            sAb + pp * 512 + (((unsigned)(lp * 8)) ^ ((unsigned)((pp & 7) << 4)))) = v;
    }
    __syncthreads();

    const int lane = tid & 63;
    const int wid  = tid >> 6;           // 0..7
    const int rowb = (wid & 3) * 64;     // feature slice
    const int pb   = (wid >> 2) * 64;    // point half
    const int arow = lane & 15;
    const int kgrp = lane >> 4;
    const int bcol = lane & 15;

    f32x4 acc[4][4];

    auto epilogue = [&](const float* __restrict__ bias) {
        #pragma unroll
        for (int rt = 0; rt < 4; ++rt) {
            const int f0 = rowb + rt * 16 + kgrp * 4;
            const float4 bv = *reinterpret_cast<const float4*>(bias + f0);
            #pragma unroll
            for (int ct = 0; ct < 4; ++ct) {
                const int pp = pb + ct * 16 + bcol;
                const float v0 = fmaxf(acc[rt][ct][0] + bv.x, 0.0f);
                const float v1 = fmaxf(acc[rt][ct][1] + bv.y, 0.0f);
                const float v2 = fmaxf(acc[rt][ct][2] + bv.z, 0.0f);
                const float v3 = fmaxf(acc[rt][ct][3] + bv.w, 0.0f);
                uint2 pk;
                pk.x = cvtpk(v0, v1);
                pk.y = cvtpk(v2, v3);
                *reinterpret_cast<uint2*>(
                    sAb + pp * 512 + (((unsigned)(2 * f0)) ^ ((unsigned)((pp & 7) << 4)))) = pk;
            }
        }
    };

    // ---- layer 1 ----
    {
        #pragma unroll
        for (int rt = 0; rt < 4; ++rt)
            #pragma unroll
            for (int ct = 0; ct < 4; ++ct) acc[rt][ct] = f32x4{0.f, 0.f, 0.f, 0.f};

        s16x8 wfr[4];
        #pragma unroll
        for (int rt = 0; rt < 4; ++rt)
            wfr[rt] = *reinterpret_cast<const s16x8*>(wt + (rowb + rt * 16 + arow) * 32 + kgrp * 8);
        #pragma unroll
        for (int ct = 0; ct < 4; ++ct) {
            const int pp = pb + ct * 16 + bcol;
            const s16x8 bfr = *reinterpret_cast<const s16x8*>(
                sAb + pp * 512 + (((unsigned)(kgrp * 16)) ^ ((unsigned)((pp & 7) << 4))));
            #pragma unroll
            for (int rt = 0; rt < 4; ++rt)
                acc[rt][ct] = mfma_bf16(wfr[rt], bfr, acc[rt][ct]);
        }
        __syncthreads();
        epilogue(b1);
        __syncthreads();
    }

    // ---- layers 2 & 3 ----
    #pragma unroll 1
    for (int layer = 0; layer < 2; ++layer) {
        const unsigned short* __restrict__ W = wt + 8192 + (layer << 16);
        #pragma unroll
        for (int rt = 0; rt < 4; ++rt)
            #pragma unroll
            for (int ct = 0; ct < 4; ++ct) acc[rt][ct] = f32x4{0.f, 0.f, 0.f, 0.f};

        for (int ks = 0; ks < 8; ++ks) {
            s16x8 wfr[4];
            #pragma unroll
            for (int rt = 0; rt < 4; ++rt)
                wfr[rt] = *reinterpret_cast<const s16x8*>(
                    W + (rowb + rt * 16 + arow) * 256 + ks * 32 + kgrp * 8);
            #pragma unroll
            for (int ct = 0; ct < 4; ++ct) {
                const int pp = pb + ct * 16 + bcol;
                const s16x8 bfr = *reinterpret_cast<const s16x8*>(
                    sAb + pp * 512 + (((unsigned)(ks * 64 + kgrp * 16)) ^ ((unsigned)((pp & 7) << 4))));
                #pragma unroll
                for (int rt = 0; rt < 4; ++rt)
                    acc[rt][ct] = mfma_bf16(wfr[rt], bfr, acc[rt][ct]);
            }
        }
        __syncthreads();
        epilogue(layer == 0 ? b2 : b3);
        __syncthreads();
    }

    // ---- layer 4 via MFMA: 8 waves x 16 points = 128 ----
    {
        const unsigned short* __restrict__ W4 = wt + 139264;
        const int pp = wid * 16 + bcol;
        f32x4 a4 = f32x4{0.f, 0.f, 0.f, 0.f};
        #pragma unroll
        for (int ks = 0; ks < 8; ++ks) {
            const s16x8 wfr = *reinterpret_cast<const s16x8*>(W4 + arow * 256 + ks * 32 + kgrp * 8);
            const s16x8 bfr = *reinterpret_cast<const s16x8*>(
                sAb + pp * 512 + (((unsigned)(ks * 64 + kgrp * 16)) ^ ((unsigned)((pp & 7) << 4))));
            a4 = mfma_bf16(wfr, bfr, a4);
        }
        if (kgrp == 0) {
            const int pi = p0 + pp;
            if (pi < N) {
                #pragma unroll
                for (int c = 0; c < 3; ++c) {
                    const float z = a4[c] + b4[c];
                    out[pi * 3 + c] = 1.0f / (1.0f + expf(-z));
                }
            }
        }
    }
}

// ---- fused fallback (fp32 table) — unchanged, BR=64/256t ----
__global__ __launch_bounds__(NTHREADS, 3)
void fused_hashmlp(const float* __restrict__ x, const float* __restrict__ table,
                   const unsigned short* __restrict__ wt,
                   const float* __restrict__ b1, const float* __restrict__ b2,
                   const float* __restrict__ b3,
                   const float* __restrict__ w4, const float* __restrict__ b4,
                   float* __restrict__ out, int N)
{
    __shared__ float sX[BR][3];
    __shared__ unsigned short sA[BR * 256];
    const int tid = threadIdx.x;
    const int p0  = blockIdx.x * BR;
    if (p0 >= N) return;
    char* sAb = (char*)sA;

    if (tid < BR * 3) sX[tid / 3][tid % 3] = x[p0 * 3 + tid];
    __syncthreads();

    #pragma unroll
    for (int it = 0; it < 4; ++it) {
        const int task = it * NTHREADS + tid;
        const int l = task >> 6;
        const int p = task & 63;
        const float sc  = c_scale[l];
        const float inv = (1.0f / 1.5f);
        const float px = sX[p][0] * inv * sc + 0.5f;
        const float py = sX[p][1] * inv * sc + 0.5f;
        const float pz = sX[p][2] * inv * sc + 0.5f;
        const float fx = floorf(px), fy = floorf(py), fz = floorf(pz);
        const float rx = px - fx, ry = py - fy, rz = pz - fz;
        const unsigned ux = (unsigned)fx, uy = (unsigned)fy, uz = (unsigned)fz;
        const unsigned off = c_off[l];
        const unsigned r1  = c_res1[l];
        const bool dense = (l < 5);
        float ax = 0.0f, ay = 0.0f;
        #pragma unroll
        for (int c = 0; c < 8; ++c) {
            const unsigned bx = c & 1, by = (c >> 1) & 1, bz = (c >> 2) & 1;
            const unsigned cx = ux + bx, cy = uy + by, cz = uz + bz;
            const float wx = bx ? rx : (1.0f - rx);
            const float wy = by ? ry : (1.0f - ry);
            const float wz = bz ? rz : (1.0f - rz);
            const float w = wx * wy * wz;
            unsigned idx;
            if (dense) idx = cx + cy * r1 + cz * r1 * r1;
            else       idx = (cx ^ (cy * 2654435761u) ^ (cz * 805459861u)) & 524287u;
            const float2 tv = *reinterpret_cast<const float2*>(table + 2u * (idx + off));
            ax = fmaf(w, tv.x, ax);
            ay = fmaf(w, tv.y, ay);
        }
        const unsigned pack = (unsigned)f2bf(ax) | ((unsigned)f2bf(ay) << 16);
        *reinterpret_cast<unsigned*>(sAb + p * 512 + ((l * 4) ^ ((p & 7) << 4))) = pack;
    }
    __syncthreads();

    const int lane = tid & 63;
    const int wid  = tid >> 6;
    const int rowb = wid * 64;
    const int arow = lane & 15;
    const int kgrp = lane >> 4;
    const int bcol = lane & 15;

    f32x4 acc[4][4];

    auto epilogue = [&](const float* __restrict__ bias) {
        #pragma unroll
        for (int rt = 0; rt < 4; ++rt) {
            const int f0 = rowb + rt * 16 + kgrp * 4;
            const float4 bv = *reinterpret_cast<const float4*>(bias + f0);
            #pragma unroll
            for (int ct = 0; ct < 4; ++ct) {
                const int p = ct * 16 + bcol;
                const float v0 = fmaxf(acc[rt][ct][0] + bv.x, 0.0f);
                const float v1 = fmaxf(acc[rt][ct][1] + bv.y, 0.0f);
                const float v2 = fmaxf(acc[rt][ct][2] + bv.z, 0.0f);
                const float v3 = fmaxf(acc[rt][ct][3] + bv.w, 0.0f);
                uint2 pk;
                pk.x = (unsigned)f2bf(v0) | ((unsigned)f2bf(v1) << 16);
                pk.y = (unsigned)f2bf(v2) | ((unsigned)f2bf(v3) << 16);
                *reinterpret_cast<uint2*>(
                    sAb + p * 512 + (((unsigned)(2 * f0)) ^ ((unsigned)((p & 7) << 4)))) = pk;
            }
        }
    };

    {
        #pragma unroll
        for (int rt = 0; rt < 4; ++rt)
            #pragma unroll
            for (int ct = 0; ct < 4; ++ct) acc[rt][ct] = f32x4{0.f, 0.f, 0.f, 0.f};
        s16x8 wfr[4];
        #pragma unroll
        for (int rt = 0; rt < 4; ++rt)
            wfr[rt] = *reinterpret_cast<const s16x8*>(wt + (rowb + rt * 16 + arow) * 32 + kgrp * 8);
        #pragma unroll
        for (int ct = 0; ct < 4; ++ct) {
            const int p = ct * 16 + bcol;
            const s16x8 bfr = *reinterpret_cast<const s16x8*>(
                sAb + p * 512 + (((unsigned)(kgrp * 16)) ^ ((unsigned)((p & 7) << 4))));
            #pragma unroll
            for (int rt = 0; rt < 4; ++rt)
                acc[rt][ct] = mfma_bf16(wfr[rt], bfr, acc[rt][ct]);
        }
        __syncthreads();
        epilogue(b1);
        __syncthreads();
    }

    #pragma unroll 1
    for (int layer = 0; layer < 2; ++layer) {
        const unsigned short* __restrict__ W = wt + 8192 + (layer << 16);
        #pragma unroll
        for (int rt = 0; rt < 4; ++rt)
            #pragma unroll
            for (int ct = 0; ct < 4; ++ct) acc[rt][ct] = f32x4{0.f, 0.f, 0.f, 0.f};
        for (int ks = 0; ks < 8; ++ks) {
            s16x8 wfr[4];
            #pragma unroll
            for (int rt = 0; rt < 4; ++rt)
                wfr[rt] = *reinterpret_cast<const s16x8*>(
                    W + (rowb + rt * 16 + arow) * 256 + ks * 32 + kgrp * 8);
            #pragma unroll
            for (int ct = 0; ct < 4; ++ct) {
                const int p = ct * 16 + bcol;
                const s16x8 bfr = *reinterpret_cast<const s16x8*>(
                    sAb + p * 512 + (((unsigned)(ks * 64 + kgrp * 16)) ^ ((unsigned)((p & 7) << 4))));
                #pragma unroll
                for (int rt = 0; rt < 4; ++rt)
                    acc[rt][ct] = mfma_bf16(wfr[rt], bfr, acc[rt][ct]);
            }
        }
        __syncthreads();
        epilogue(layer == 0 ? b2 : b3);
        __syncthreads();
    }

    if (tid < BR * 3) {
        const int r = tid / 3;
        const int c = tid - 3 * r;
        float z0 = 0.0f, z1 = 0.0f;
        for (int kb = 0; kb < 32; kb += 2) {
            const s16x8 hv0 = *reinterpret_cast<const s16x8*>(
                sAb + r * 512 + (((unsigned)(kb * 16)) ^ ((unsigned)((r & 7) << 4))));
            const s16x8 hv1 = *reinterpret_cast<const s16x8*>(
                sAb + r * 512 + (((unsigned)((kb + 1) * 16)) ^ ((unsigned)((r & 7) << 4))));
            #pragma unroll
            for (int j = 0; j < 8; ++j) {
                z0 = fmaf(bf2f((unsigned short)hv0[j]), w4[(kb * 8 + j) * 3 + c], z0);
                z1 = fmaf(bf2f((unsigned short)hv1[j]), w4[((kb + 1) * 8 + j) * 3 + c], z1);
            }
        }
        const float z = z0 + z1 + b4[c];
        const int pi = p0 + r;
        if (pi < N) out[pi * 3 + c] = 1.0f / (1.0f + expf(-z));
    }
}

extern "C" void kernel_launch(void* const* d_in, const int* in_sizes, int n_in,
                              void* d_out, int out_size, void* d_ws, size_t ws_size,
                              hipStream_t stream) {
    const float* x     = (const float*)d_in[0];
    const float* table = (const float*)d_in[1];
    const float* w1    = (const float*)d_in[2];
    const float* b1    = (const float*)d_in[3];
    const float* w2    = (const float*)d_in[4];
    const float* b2    = (const float*)d_in[5];
    const float* w3    = (const float*)d_in[6];
    const float* b3    = (const float*)d_in[7];
    const float* w4    = (const float*)d_in[8];
    const float* b4    = (const float*)d_in[9];
    float* out = (float*)d_out;

    const int N = in_sizes[0] / 3;

    const size_t W_ELEMS    = 143360;
    const size_t TOTAL_E    = 6119864;
    const size_t wt_bytes   = W_ELEMS * 2;
    const size_t tbl_bytes  = TOTAL_E * 2;
    const size_t need_bf    = wt_bytes + tbl_bytes;       // 12526448
    const size_t FEAT_BYTES = (size_t)N * 64;
    const size_t need_split = need_bf + FEAT_BYTES;

    unsigned short* wsw  = (unsigned short*)d_ws;
    unsigned short* tbf8 = (unsigned short*)((char*)d_ws + wt_bytes);
    uint2* feat2 = (uint2*)((char*)d_ws + need_bf);

    hipLaunchKernelGGL(convert_w, dim3(560), dim3(256), 0, stream, w1, w2, w3, w4, wsw);

    if (ws_size >= need_split) {
        hipLaunchKernelGGL(convert_table_fp8, dim3((unsigned)((TOTAL_E + 255) / 256)), dim3(256),
                           0, stream, table, tbf8, (int)TOTAL_E);
        hipLaunchKernelGGL(encode_kernel, dim3((N + 255) / 256, 8), dim3(256), 0, stream,
                           x, tbf8, feat2, N);
        hipLaunchKernelGGL(mlp_kernel, dim3((N + MBR - 1) / MBR), dim3(MTHREADS), 0, stream,
                           feat2, wsw, b1, b2, b3, b4, out, N);
    } else {
        hipLaunchKernelGGL(fused_hashmlp, dim3((N + BR - 1) / BR), dim3(NTHREADS), 0, stream,
                           x, table, wsw, b1, b2, b3, w4, b4, out, N);
    }
}